// Round 20
// baseline (109.601 us; speedup 1.0000x reference)
//
#include <hip/hip_runtime.h>

#define SEQ    512
#define PRED   336
#define NPTS   8
#define NG     8
#define NCOMP  18
#define BATCH  8192
#define TAU    1e-4f
#define NEGBIG (-3.402823466e+38f)
#define BIGI   0x7fffffff

typedef __bf16 bf16x8 __attribute__((ext_vector_type(8)));
typedef float  f32x4  __attribute__((ext_vector_type(4)));

__device__ __forceinline__ void gload_lds16(const __bf16* g, __bf16* l) {
  __builtin_amdgcn_global_load_lds(
      (const __attribute__((address_space(1))) unsigned int*)(const void*)g,
      (__attribute__((address_space(3))) unsigned int*)(void*)l, 16, 0, 0);
}

// ---------------- k_pack: f32 -> (hi,lo) bf16 + composite params.
// A: fragment-order [row16][H=k/32][part][lane=lk*16+lr][8]  (direct-to-VGPR in k1)
// B: STAGE-ORDER [nt][H][chunk c][8]: c = part*512 + lk*128 + col
__global__ __launch_bounds__(256) void k_pack(
    const float* __restrict__ x, const float* __restrict__ Wp,
    const float* __restrict__ Wc, const float* __restrict__ bc,
    __bf16* __restrict__ Apk, __bf16* __restrict__ Bpk,
    float* __restrict__ params)
{
  const int lane = threadIdx.x & 63, wid = threadIdx.x >> 6;
  const int b = blockIdx.x;
  if (b < BATCH / 4) {                      // ---- A part
    const int row = b * 4 + wid;
    const float* src = x + (size_t)row * SEQ;
    const float last = src[SEQ - 1];
    float4 u0 = *(const float4*)&src[lane * 8];
    float4 u1 = *(const float4*)&src[lane * 8 + 4];
    float xc[8] = {u0.x - last, u0.y - last, u0.z - last, u0.w - last,
                   u1.x - last, u1.y - last, u1.z - last, u1.w - last};
    bf16x8 h, l;
#pragma unroll
    for (int j = 0; j < 8; ++j) {
      __bf16 hb = (__bf16)xc[j];
      float rest = xc[j] - (float)hb;
      h[j] = hb; l[j] = (__bf16)rest;
    }
    const int H = lane >> 2, lk = lane & 3;
    const size_t base = ((size_t)(row >> 4) * 32 + H * 2) * 512
                      + (size_t)(lk * 16 + (row & 15)) * 8;
    *(bf16x8*)&Apk[base]       = h;
    *(bf16x8*)&Apk[base + 512] = l;

    float pd[NCOMP];
#pragma unroll
    for (int s = 0; s < NCOMP; ++s) {
      const float* w = Wc + (size_t)s * SEQ + lane * 8;
      float4 w0 = *(const float4*)(w);
      float4 w1 = *(const float4*)(w + 4);
      float a = 0.f;
      a = fmaf(xc[0], w0.x, a); a = fmaf(xc[1], w0.y, a);
      a = fmaf(xc[2], w0.z, a); a = fmaf(xc[3], w0.w, a);
      a = fmaf(xc[4], w1.x, a); a = fmaf(xc[5], w1.y, a);
      a = fmaf(xc[6], w1.z, a); a = fmaf(xc[7], w1.w, a);
      pd[s] = a;
    }
#pragma unroll
    for (int d = 1; d < 64; d <<= 1)
#pragma unroll
      for (int s = 0; s < NCOMP; ++s) pd[s] += __shfl_xor(pd[s], d);
    if (lane < NCOMP) params[(size_t)row * NCOMP + lane] = pd[lane] + bc[lane];
  } else {                                  // ---- B part (padded to 384 cols/group)
    const int row = (b - BATCH / 4) * 4 + wid;      // 0..3071 padded col index
    const int g = row / 384, local = row - g * 384;
    bf16x8 h, l;
    if (local < PRED) {
      const float* src = Wp + (size_t)(g * PRED + local) * SEQ;
      float4 u0 = *(const float4*)&src[lane * 8];
      float4 u1 = *(const float4*)&src[lane * 8 + 4];
      float v[8] = {u0.x, u0.y, u0.z, u0.w, u1.x, u1.y, u1.z, u1.w};
#pragma unroll
      for (int j = 0; j < 8; ++j) {
        __bf16 hb = (__bf16)v[j];
        float rest = v[j] - (float)hb;
        h[j] = hb; l[j] = (__bf16)rest;
      }
    } else {
#pragma unroll
      for (int j = 0; j < 8; ++j) { h[j] = (__bf16)0.f; l[j] = (__bf16)0.f; }
    }
    const int nt = row >> 7, col = row & 127;
    const int H = lane >> 2, lk = lane & 3;
    const size_t base = (size_t)nt * 131072 + (size_t)H * 8192
                      + (size_t)(lk * 128 + col) * 8;
    *(bf16x8*)&Bpk[base]        = h;
    *(bf16x8*)&Bpk[base + 4096] = l;
  }
}

// ---------------- k1: 3-term hi/lo MFMA GEMM, coalesced staging + counted vmcnt
// BM=128 x BN=128 (padded), BK=32, 16 phases, 4 waves (32 rows each: m=2, n=8).
// A: global->VGPR (fragment-order, dbuf). B: LDS ring-3 x 16KB = 48KB -> 3 blk/CU.
// Per phase exactly 8 VMEM issues (4 STAGE + 4 ALOAD) -> vmcnt(8) at the barrier
// retires all prior-phase loads without draining this phase's.
// PROLOGUE IS vmcnt(0): issue order of STAGE(0/1)/ALOAD(0) is compiler-chosen,
// so a counted wait there is unsound (round-19 race).
__global__ __launch_bounds__(256, 3) void k1_mfma(
    const __bf16* __restrict__ Apk, const __bf16* __restrict__ Bpk,
    const float* __restrict__ bp,
    float* __restrict__ t1v, int* __restrict__ t1i,
    float* __restrict__ t2v, int* __restrict__ t2i)
{
  __shared__ __bf16 sbuf[3][8192];          // 48 KiB
  const int tid  = threadIdx.x;
  const int lane = tid & 63, wid = tid >> 6;
  const int bid  = blockIdx.x;
  const int v    = (bid & 7) * 192 + (bid >> 3);  // bijective (1536 = 8*192)
  const int mt   = v / 24;                        // 0..63
  const int nt   = v % 24;                        // 0..23
  const int row0 = mt * 128;

  // B staging: 1024 chunks/phase, 4/thread; src AND dest linear in c
  const __bf16* gsrc[4];
  int dsti[4];
#pragma unroll
  for (int i = 0; i < 4; ++i) {
    const int c = i * 256 + tid;
    dsti[i] = c * 8;
    gsrc[i] = Bpk + (size_t)nt * 131072 + (size_t)c * 8;
  }
  // A fragment bases (per m)
  const __bf16* abase[2];
#pragma unroll
  for (int m = 0; m < 2; ++m)
    abase[m] = Apk + (size_t)(mt * 8 + wid * 2 + m) * 16384 + (size_t)lane * 8;

  const int lr = lane & 15, lk2 = lane >> 4;
  const int fb = lk2 * 1024 + lr * 8;             // + n*128 ; lo at +4096

  f32x4 acc[2][8];
#pragma unroll
  for (int m = 0; m < 2; ++m)
#pragma unroll
    for (int n = 0; n < 8; ++n) acc[m][n] = (f32x4){0.f, 0.f, 0.f, 0.f};

  bf16x8 ah[2][2], al[2][2];                      // [buf][m]

#define STAGE(H, WP) do { \
  _Pragma("unroll") \
  for (int i_ = 0; i_ < 4; ++i_) gload_lds16(gsrc[i_] + (H) * 8192, (WP) + dsti[i_]); \
} while (0)
#define ALOAD(H, S) do { \
  _Pragma("unroll") \
  for (int m_ = 0; m_ < 2; ++m_) { \
    ah[S][m_] = *(const bf16x8*)(abase[m_] + (H) * 1024); \
    al[S][m_] = *(const bf16x8*)(abase[m_] + (H) * 1024 + 512); } \
} while (0)

  // prologue: full drain (order-insensitive; the counted wait here was the race)
  STAGE(0, &sbuf[0][0]);
  STAGE(1, &sbuf[1][0]);
  ALOAD(0, 0);
  asm volatile("s_waitcnt vmcnt(0)" ::: "memory");
  asm volatile("s_barrier" ::: "memory");

#pragma unroll
  for (int H = 0; H < 16; ++H) {
    const int cur = H & 1;
    if (H < 14) STAGE(H + 2, &sbuf[(H + 2) % 3][0]);   // depth-2 prefetch
    if (H < 15) ALOAD(H + 1, cur ^ 1);
    const __bf16* rs = &sbuf[H % 3][0];
    bf16x8 bh[8], bl[8];
#pragma unroll
    for (int n = 0; n < 8; ++n) {
      bh[n] = *(const bf16x8*)&rs[fb + n * 128];
      bl[n] = *(const bf16x8*)&rs[4096 + fb + n * 128];
    }
#pragma unroll
    for (int n = 0; n < 8; ++n)
#pragma unroll
      for (int m = 0; m < 2; ++m) {
        acc[m][n] = __builtin_amdgcn_mfma_f32_16x16x32_bf16(ah[cur][m], bh[n], acc[m][n], 0, 0, 0);
        acc[m][n] = __builtin_amdgcn_mfma_f32_16x16x32_bf16(ah[cur][m], bl[n], acc[m][n], 0, 0, 0);
        acc[m][n] = __builtin_amdgcn_mfma_f32_16x16x32_bf16(al[cur][m], bh[n], acc[m][n], 0, 0, 0);
      }
    if (H < 14) {
      // phase issued exactly 8 VMEM ops -> retire all prior-phase loads
      asm volatile("s_waitcnt vmcnt(8)" ::: "memory");
      asm volatile("s_barrier" ::: "memory");
    } else if (H == 14) {
      // phase issued 4 (ALOAD(15) only) -> retire STAGE(15)+ALOAD(14)
      asm volatile("s_waitcnt vmcnt(4)" ::: "memory");
      asm volatile("s_barrier" ::: "memory");
    }
  }
#undef STAGE
#undef ALOAD

  // epilogue: bias (pad cols -> NEGBIG) + per-row top-2 with indices
  const int g = nt / 3, colg0 = (nt % 3) * 128;
  float bias[8];
#pragma unroll
  for (int n = 0; n < 8; ++n) {
    const int col = colg0 + n * 16 + lr;
    bias[n] = (col < PRED) ? bp[g * PRED + col] : NEGBIG;
  }

#define GT(a,ia,b,ib) ((a) > (b) || ((a) == (b) && (ia) < (ib)))
#pragma unroll
  for (int m = 0; m < 2; ++m)
#pragma unroll
    for (int r = 0; r < 4; ++r) {
      float v1 = NEGBIG, v2 = NEGBIG; int i1 = BIGI, i2 = BIGI;
#pragma unroll
      for (int n = 0; n < 8; ++n) {
        const float vv = acc[m][n][r] + bias[n];
        const int col = colg0 + n * 16 + lr;
        if (vv > v1)      { v2 = v1; i2 = i1; v1 = vv; i1 = col; }
        else if (vv > v2) { v2 = vv; i2 = col; }
      }
#pragma unroll
      for (int d = 1; d < 16; d <<= 1) {
        const float o1 = __shfl_xor(v1, d), o2 = __shfl_xor(v2, d);
        const int   p1 = __shfl_xor(i1, d), p2 = __shfl_xor(i2, d);
        if (GT(o1, p1, v1, i1)) {
          if (GT(v1, i1, o2, p2)) { v2 = v1; i2 = i1; }
          else                    { v2 = o2; i2 = p2; }
          v1 = o1; i1 = p1;
        } else if (GT(o1, p1, v2, i2)) { v2 = o1; i2 = p1; }
      }
      if (lr == 0) {
        const int rowg = row0 + wid * 32 + m * 16 + lk2 * 4 + r;
        const int o = rowg * 24 + nt;
        t1v[o] = v1; t1i[o] = i1; t2v[o] = v2; t2i[o] = i2;
      }
    }
#undef GT
}

// ---------------- k23: candidate merge + rare f64 recheck + sort + assembly.
__global__ __launch_bounds__(256) void k23_out(
    const float* __restrict__ x, const float* __restrict__ Wp,
    const float* __restrict__ bp, const float* __restrict__ params,
    const float* __restrict__ t1v, const int* __restrict__ t1i,
    const float* __restrict__ t2v, const int* __restrict__ t2i,
    float* __restrict__ out)
{
  const int lane = threadIdx.x & 63;
  const int wid  = threadIdx.x >> 6;
  const int row  = blockIdx.x * 4 + wid;

  float v[6]; int ix[6];
  float v1 = NEGBIG; int i1 = BIGI; bool flag = false;
#pragma unroll
  for (int s = 0; s < 6; ++s) { v[s] = NEGBIG; ix[s] = BIGI; }
  if (lane < 8) {
    const int base = row * 24 + lane * 3;
#pragma unroll
    for (int t = 0; t < 3; ++t) {
      v[2 * t]     = t1v[base + t]; ix[2 * t]     = t1i[base + t];
      v[2 * t + 1] = t2v[base + t]; ix[2 * t + 1] = t2i[base + t];
    }
#pragma unroll
    for (int s = 0; s < 6; ++s)
      if (v[s] > v1 || (v[s] == v1 && ix[s] < i1)) { v1 = v[s]; i1 = ix[s]; }
    int cnt = 0;
#pragma unroll
    for (int s = 0; s < 6; ++s) cnt += (v[s] >= v1 - TAU) ? 1 : 0;
    flag = (cnt >= 2);
  }

  int p[8];
#pragma unroll
  for (int j = 0; j < 8; ++j) p[j] = __shfl(i1, j);

  unsigned long long mb = __ballot(flag);
  if (mb) {
    const float* xr = x + (size_t)row * SEQ;
    const float last = xr[SEQ - 1];
    double xd[8];
    {
      float4 a0 = *(const float4*)&xr[lane * 8];
      float4 a1 = *(const float4*)&xr[lane * 8 + 4];
      xd[0]=(double)(a0.x-last); xd[1]=(double)(a0.y-last); xd[2]=(double)(a0.z-last); xd[3]=(double)(a0.w-last);
      xd[4]=(double)(a1.x-last); xd[5]=(double)(a1.y-last); xd[6]=(double)(a1.z-last); xd[7]=(double)(a1.w-last);
    }
    while (mb) {
      const int L = (int)__ffsll((long long)mb) - 1; mb &= mb - 1;  // L = group
      const float bv1 = __shfl(v1, L);
      double bb = -1e300; int bi = BIGI;
#pragma unroll
      for (int s = 0; s < 6; ++s) {
        const float vs = __shfl(v[s], L);
        const int   is = __shfl(ix[s], L);
        if (vs >= bv1 - TAU) {                       // wave-uniform
          const float* w = Wp + ((size_t)L * PRED + is) * SEQ + lane * 8;
          float4 w0 = *(const float4*)w, w1 = *(const float4*)(w + 4);
          double t = 0.0;
          t += xd[0]*(double)w0.x + xd[1]*(double)w0.y + xd[2]*(double)w0.z + xd[3]*(double)w0.w;
          t += xd[4]*(double)w1.x + xd[5]*(double)w1.y + xd[6]*(double)w1.z + xd[7]*(double)w1.w;
#pragma unroll
          for (int d = 1; d < 64; d <<= 1) t += __shfl_xor(t, d);
          t += (double)bp[L * PRED + is];
          if (t > bb || (t == bb && is < bi)) { bb = t; bi = is; }
        }
      }
      p[L] = bi;
    }
  }

#define CSW(a,b) { int lo_ = min(p[a], p[b]); int hi_ = max(p[a], p[b]); p[a] = lo_; p[b] = hi_; }
  CSW(0,1) CSW(2,3) CSW(4,5) CSW(6,7)
  CSW(0,2) CSW(1,3) CSW(4,6) CSW(5,7)
  CSW(1,2) CSW(5,6)
  CSW(0,4) CSW(1,5) CSW(2,6) CSW(3,7)
  CSW(2,4) CSW(3,5)
  CSW(1,2) CSW(3,4) CSW(5,6)
#undef CSW

  const float last = x[(size_t)row * SEQ + (SEQ - 1)];
  float pd[NCOMP];
#pragma unroll
  for (int s = 0; s < NCOMP; ++s) pd[s] = params[(size_t)row * NCOMP + s];

  for (int t = lane; t < PRED; t += 64) {
    int slot = 0;
#pragma unroll
    for (int j = 0; j < 8; ++j) slot += (p[j] <= t) ? 1 : 0;
    out[(size_t)row * PRED + t] = fmaf(pd[slot * 2], (float)t, pd[slot * 2 + 1]) + last;
  }
}

extern "C" void kernel_launch(void* const* d_in, const int* in_sizes, int n_in,
                              void* d_out, int out_size, void* d_ws, size_t ws_size,
                              hipStream_t stream)
{
  const float* x  = (const float*)d_in[0];
  const float* Wp = (const float*)d_in[1];
  const float* bp = (const float*)d_in[2];
  const float* Wc = (const float*)d_in[3];
  const float* bc = (const float*)d_in[4];
  float* out = (float*)d_out;

  char* w = (char*)d_ws;
  __bf16* Apk = (__bf16*)w;  w += (size_t)BATCH * 1024 * 2;          // 16 MB
  __bf16* Bpk = (__bf16*)w;  w += (size_t)24 * 131072 * 2;           // 6 MB (stage-order)
  float* t1v  = (float*)w;   w += (size_t)BATCH * 24 * 4;
  int*   t1i  = (int*)w;     w += (size_t)BATCH * 24 * 4;
  float* t2v  = (float*)w;   w += (size_t)BATCH * 24 * 4;
  int*   t2i  = (int*)w;     w += (size_t)BATCH * 24 * 4;
  float* params = (float*)w; w += (size_t)BATCH * NCOMP * 4;         // 0.59 MB

  hipLaunchKernelGGL(k_pack, dim3(BATCH / 4 + 3072 / 4), dim3(256), 0, stream,
                     x, Wp, Wc, bc, Apk, Bpk, params);
  hipLaunchKernelGGL(k1_mfma, dim3(1536), dim3(256), 0, stream,
                     Apk, Bpk, bp, t1v, t1i, t2v, t2i);
  hipLaunchKernelGGL(k23_out, dim3(BATCH / 4), dim3(256), 0, stream,
                     x, Wp, bp, params, t1v, t1i, t2v, t2i, out);
}

// Round 21
// 107.870 us; speedup vs baseline: 1.0160x; 1.0160x over previous
//
#include <hip/hip_runtime.h>

#define SEQ    512
#define PRED   336
#define NPTS   8
#define NG     8
#define NCOMP  18
#define BATCH  8192
#define TAU    1e-4f
#define NEGBIG (-3.402823466e+38f)
#define BIGI   0x7fffffff

typedef __bf16 bf16x8 __attribute__((ext_vector_type(8)));
typedef float  f32x4  __attribute__((ext_vector_type(4)));

__device__ __forceinline__ void gload_lds16(const __bf16* g, __bf16* l) {
  __builtin_amdgcn_global_load_lds(
      (const __attribute__((address_space(1))) unsigned int*)(const void*)g,
      (__attribute__((address_space(3))) unsigned int*)(void*)l, 16, 0, 0);
}

// ---------------- k_pack: f32 -> (hi,lo) bf16 + composite params.
// A: fragment-order [row16][H=k/32][part][lane=lk*16+lr][8]  (direct-to-VGPR in k1)
// B: STAGE-ORDER [nt][H][chunk c][8]: c = part*512 + lk*128 + col
__global__ __launch_bounds__(256) void k_pack(
    const float* __restrict__ x, const float* __restrict__ Wp,
    const float* __restrict__ Wc, const float* __restrict__ bc,
    __bf16* __restrict__ Apk, __bf16* __restrict__ Bpk,
    float* __restrict__ params)
{
  const int lane = threadIdx.x & 63, wid = threadIdx.x >> 6;
  const int b = blockIdx.x;
  if (b < BATCH / 4) {                      // ---- A part
    const int row = b * 4 + wid;
    const float* src = x + (size_t)row * SEQ;
    const float last = src[SEQ - 1];
    float4 u0 = *(const float4*)&src[lane * 8];
    float4 u1 = *(const float4*)&src[lane * 8 + 4];
    float xc[8] = {u0.x - last, u0.y - last, u0.z - last, u0.w - last,
                   u1.x - last, u1.y - last, u1.z - last, u1.w - last};
    bf16x8 h, l;
#pragma unroll
    for (int j = 0; j < 8; ++j) {
      __bf16 hb = (__bf16)xc[j];
      float rest = xc[j] - (float)hb;
      h[j] = hb; l[j] = (__bf16)rest;
    }
    const int H = lane >> 2, lk = lane & 3;
    const size_t base = ((size_t)(row >> 4) * 32 + H * 2) * 512
                      + (size_t)(lk * 16 + (row & 15)) * 8;
    *(bf16x8*)&Apk[base]       = h;
    *(bf16x8*)&Apk[base + 512] = l;

    float pd[NCOMP];
#pragma unroll
    for (int s = 0; s < NCOMP; ++s) {
      const float* w = Wc + (size_t)s * SEQ + lane * 8;
      float4 w0 = *(const float4*)(w);
      float4 w1 = *(const float4*)(w + 4);
      float a = 0.f;
      a = fmaf(xc[0], w0.x, a); a = fmaf(xc[1], w0.y, a);
      a = fmaf(xc[2], w0.z, a); a = fmaf(xc[3], w0.w, a);
      a = fmaf(xc[4], w1.x, a); a = fmaf(xc[5], w1.y, a);
      a = fmaf(xc[6], w1.z, a); a = fmaf(xc[7], w1.w, a);
      pd[s] = a;
    }
#pragma unroll
    for (int d = 1; d < 64; d <<= 1)
#pragma unroll
      for (int s = 0; s < NCOMP; ++s) pd[s] += __shfl_xor(pd[s], d);
    if (lane < NCOMP) params[(size_t)row * NCOMP + lane] = pd[lane] + bc[lane];
  } else {                                  // ---- B part (padded to 384 cols/group)
    const int row = (b - BATCH / 4) * 4 + wid;      // 0..3071 padded col index
    const int g = row / 384, local = row - g * 384;
    bf16x8 h, l;
    if (local < PRED) {
      const float* src = Wp + (size_t)(g * PRED + local) * SEQ;
      float4 u0 = *(const float4*)&src[lane * 8];
      float4 u1 = *(const float4*)&src[lane * 8 + 4];
      float v[8] = {u0.x, u0.y, u0.z, u0.w, u1.x, u1.y, u1.z, u1.w};
#pragma unroll
      for (int j = 0; j < 8; ++j) {
        __bf16 hb = (__bf16)v[j];
        float rest = v[j] - (float)hb;
        h[j] = hb; l[j] = (__bf16)rest;
      }
    } else {
#pragma unroll
      for (int j = 0; j < 8; ++j) { h[j] = (__bf16)0.f; l[j] = (__bf16)0.f; }
    }
    const int nt = row >> 7, col = row & 127;
    const int H = lane >> 2, lk = lane & 3;
    const size_t base = (size_t)nt * 131072 + (size_t)H * 8192
                      + (size_t)(lk * 128 + col) * 8;
    *(bf16x8*)&Bpk[base]        = h;
    *(bf16x8*)&Bpk[base + 4096] = l;
  }
}

// ---------------- k1: 3-term hi/lo MFMA GEMM  (round-18 golden: coalesced staging)
// BM=128 x BN=128 (padded), BK=32, 16 phases, 4 waves (32 rows each: m=2, n=8).
// A: global->VGPR (fragment-order, dbuf). B: LDS 2x16KB -> 3 blocks/CU.
// B staging reads the STAGE-ORDER Bpk: lane-contiguous 1KB/instr, coalesced.
__global__ __launch_bounds__(256, 3) void k1_mfma(
    const __bf16* __restrict__ Apk, const __bf16* __restrict__ Bpk,
    const float* __restrict__ bp,
    float* __restrict__ t1v, int* __restrict__ t1i,
    float* __restrict__ t2v, int* __restrict__ t2i)
{
  __shared__ __bf16 sbuf[2][8192];          // 32 KiB
  const int tid  = threadIdx.x;
  const int lane = tid & 63, wid = tid >> 6;
  const int bid  = blockIdx.x;
  const int v    = (bid & 7) * 192 + (bid >> 3);  // bijective (1536 = 8*192)
  const int mt   = v / 24;                        // 0..63
  const int nt   = v % 24;                        // 0..23
  const int row0 = mt * 128;

  // B staging: 1024 chunks/phase, 4/thread; src AND dest linear in c
  const __bf16* gsrc[4];
  int dsti[4];
#pragma unroll
  for (int i = 0; i < 4; ++i) {
    const int c = i * 256 + tid;
    dsti[i] = c * 8;
    gsrc[i] = Bpk + (size_t)nt * 131072 + (size_t)c * 8;
  }
  // A fragment bases (per m)
  const __bf16* abase[2];
#pragma unroll
  for (int m = 0; m < 2; ++m)
    abase[m] = Apk + (size_t)(mt * 8 + wid * 2 + m) * 16384 + (size_t)lane * 8;

  const int lr = lane & 15, lk2 = lane >> 4;
  const int fb = lk2 * 1024 + lr * 8;             // + n*128 ; lo at +4096

  f32x4 acc[2][8];
#pragma unroll
  for (int m = 0; m < 2; ++m)
#pragma unroll
    for (int n = 0; n < 8; ++n) acc[m][n] = (f32x4){0.f, 0.f, 0.f, 0.f};

  bf16x8 ah[2][2], al[2][2];                      // [buf][m]

#define STAGE(H, WP) do { \
  _Pragma("unroll") \
  for (int i_ = 0; i_ < 4; ++i_) gload_lds16(gsrc[i_] + (H) * 8192, (WP) + dsti[i_]); \
} while (0)
#define ALOAD(H, S) do { \
  _Pragma("unroll") \
  for (int m_ = 0; m_ < 2; ++m_) { \
    ah[S][m_] = *(const bf16x8*)(abase[m_] + (H) * 1024); \
    al[S][m_] = *(const bf16x8*)(abase[m_] + (H) * 1024 + 512); } \
} while (0)

  STAGE(0, &sbuf[0][0]);
  ALOAD(0, 0);
  __syncthreads();

#pragma unroll
  for (int H = 0; H < 16; ++H) {
    const int cur = H & 1;
    if (H < 15) { STAGE(H + 1, &sbuf[cur ^ 1][0]); ALOAD(H + 1, cur ^ 1); }
    const __bf16* rs = &sbuf[cur][0];
    bf16x8 bh[8], bl[8];
#pragma unroll
    for (int n = 0; n < 8; ++n) {
      bh[n] = *(const bf16x8*)&rs[fb + n * 128];
      bl[n] = *(const bf16x8*)&rs[4096 + fb + n * 128];
    }
#pragma unroll
    for (int n = 0; n < 8; ++n)
#pragma unroll
      for (int m = 0; m < 2; ++m) {
        acc[m][n] = __builtin_amdgcn_mfma_f32_16x16x32_bf16(ah[cur][m], bh[n], acc[m][n], 0, 0, 0);
        acc[m][n] = __builtin_amdgcn_mfma_f32_16x16x32_bf16(ah[cur][m], bl[n], acc[m][n], 0, 0, 0);
        acc[m][n] = __builtin_amdgcn_mfma_f32_16x16x32_bf16(al[cur][m], bh[n], acc[m][n], 0, 0, 0);
      }
    __syncthreads();
  }
#undef STAGE
#undef ALOAD

  // epilogue: bias (pad cols -> NEGBIG) + per-row top-2 with indices
  const int g = nt / 3, colg0 = (nt % 3) * 128;
  float bias[8];
#pragma unroll
  for (int n = 0; n < 8; ++n) {
    const int col = colg0 + n * 16 + lr;
    bias[n] = (col < PRED) ? bp[g * PRED + col] : NEGBIG;
  }

#define GT(a,ia,b,ib) ((a) > (b) || ((a) == (b) && (ia) < (ib)))
#pragma unroll
  for (int m = 0; m < 2; ++m)
#pragma unroll
    for (int r = 0; r < 4; ++r) {
      float v1 = NEGBIG, v2 = NEGBIG; int i1 = BIGI, i2 = BIGI;
#pragma unroll
      for (int n = 0; n < 8; ++n) {
        const float vv = acc[m][n][r] + bias[n];
        const int col = colg0 + n * 16 + lr;
        if (vv > v1)      { v2 = v1; i2 = i1; v1 = vv; i1 = col; }
        else if (vv > v2) { v2 = vv; i2 = col; }
      }
#pragma unroll
      for (int d = 1; d < 16; d <<= 1) {
        const float o1 = __shfl_xor(v1, d), o2 = __shfl_xor(v2, d);
        const int   p1 = __shfl_xor(i1, d), p2 = __shfl_xor(i2, d);
        if (GT(o1, p1, v1, i1)) {
          if (GT(v1, i1, o2, p2)) { v2 = v1; i2 = i1; }
          else                    { v2 = o2; i2 = p2; }
          v1 = o1; i1 = p1;
        } else if (GT(o1, p1, v2, i2)) { v2 = o1; i2 = p1; }
      }
      if (lr == 0) {
        const int rowg = row0 + wid * 32 + m * 16 + lk2 * 4 + r;
        const int o = rowg * 24 + nt;
        t1v[o] = v1; t1i[o] = i1; t2v[o] = v2; t2i[o] = i2;
      }
    }
#undef GT
}

// ---------------- k23: candidate merge + rare f64 recheck + sort + assembly.
__global__ __launch_bounds__(256) void k23_out(
    const float* __restrict__ x, const float* __restrict__ Wp,
    const float* __restrict__ bp, const float* __restrict__ params,
    const float* __restrict__ t1v, const int* __restrict__ t1i,
    const float* __restrict__ t2v, const int* __restrict__ t2i,
    float* __restrict__ out)
{
  const int lane = threadIdx.x & 63;
  const int wid  = threadIdx.x >> 6;
  const int row  = blockIdx.x * 4 + wid;

  float v[6]; int ix[6];
  float v1 = NEGBIG; int i1 = BIGI; bool flag = false;
#pragma unroll
  for (int s = 0; s < 6; ++s) { v[s] = NEGBIG; ix[s] = BIGI; }
  if (lane < 8) {
    const int base = row * 24 + lane * 3;
#pragma unroll
    for (int t = 0; t < 3; ++t) {
      v[2 * t]     = t1v[base + t]; ix[2 * t]     = t1i[base + t];
      v[2 * t + 1] = t2v[base + t]; ix[2 * t + 1] = t2i[base + t];
    }
#pragma unroll
    for (int s = 0; s < 6; ++s)
      if (v[s] > v1 || (v[s] == v1 && ix[s] < i1)) { v1 = v[s]; i1 = ix[s]; }
    int cnt = 0;
#pragma unroll
    for (int s = 0; s < 6; ++s) cnt += (v[s] >= v1 - TAU) ? 1 : 0;
    flag = (cnt >= 2);
  }

  int p[8];
#pragma unroll
  for (int j = 0; j < 8; ++j) p[j] = __shfl(i1, j);

  unsigned long long mb = __ballot(flag);
  if (mb) {
    const float* xr = x + (size_t)row * SEQ;
    const float last = xr[SEQ - 1];
    double xd[8];
    {
      float4 a0 = *(const float4*)&xr[lane * 8];
      float4 a1 = *(const float4*)&xr[lane * 8 + 4];
      xd[0]=(double)(a0.x-last); xd[1]=(double)(a0.y-last); xd[2]=(double)(a0.z-last); xd[3]=(double)(a0.w-last);
      xd[4]=(double)(a1.x-last); xd[5]=(double)(a1.y-last); xd[6]=(double)(a1.z-last); xd[7]=(double)(a1.w-last);
    }
    while (mb) {
      const int L = (int)__ffsll((long long)mb) - 1; mb &= mb - 1;  // L = group
      const float bv1 = __shfl(v1, L);
      double bb = -1e300; int bi = BIGI;
#pragma unroll
      for (int s = 0; s < 6; ++s) {
        const float vs = __shfl(v[s], L);
        const int   is = __shfl(ix[s], L);
        if (vs >= bv1 - TAU) {                       // wave-uniform
          const float* w = Wp + ((size_t)L * PRED + is) * SEQ + lane * 8;
          float4 w0 = *(const float4*)w, w1 = *(const float4*)(w + 4);
          double t = 0.0;
          t += xd[0]*(double)w0.x + xd[1]*(double)w0.y + xd[2]*(double)w0.z + xd[3]*(double)w0.w;
          t += xd[4]*(double)w1.x + xd[5]*(double)w1.y + xd[6]*(double)w1.z + xd[7]*(double)w1.w;
#pragma unroll
          for (int d = 1; d < 64; d <<= 1) t += __shfl_xor(t, d);
          t += (double)bp[L * PRED + is];
          if (t > bb || (t == bb && is < bi)) { bb = t; bi = is; }
        }
      }
      p[L] = bi;
    }
  }

#define CSW(a,b) { int lo_ = min(p[a], p[b]); int hi_ = max(p[a], p[b]); p[a] = lo_; p[b] = hi_; }
  CSW(0,1) CSW(2,3) CSW(4,5) CSW(6,7)
  CSW(0,2) CSW(1,3) CSW(4,6) CSW(5,7)
  CSW(1,2) CSW(5,6)
  CSW(0,4) CSW(1,5) CSW(2,6) CSW(3,7)
  CSW(2,4) CSW(3,5)
  CSW(1,2) CSW(3,4) CSW(5,6)
#undef CSW

  const float last = x[(size_t)row * SEQ + (SEQ - 1)];
  float pd[NCOMP];
#pragma unroll
  for (int s = 0; s < NCOMP; ++s) pd[s] = params[(size_t)row * NCOMP + s];

  for (int t = lane; t < PRED; t += 64) {
    int slot = 0;
#pragma unroll
    for (int j = 0; j < 8; ++j) slot += (p[j] <= t) ? 1 : 0;
    out[(size_t)row * PRED + t] = fmaf(pd[slot * 2], (float)t, pd[slot * 2 + 1]) + last;
  }
}

extern "C" void kernel_launch(void* const* d_in, const int* in_sizes, int n_in,
                              void* d_out, int out_size, void* d_ws, size_t ws_size,
                              hipStream_t stream)
{
  const float* x  = (const float*)d_in[0];
  const float* Wp = (const float*)d_in[1];
  const float* bp = (const float*)d_in[2];
  const float* Wc = (const float*)d_in[3];
  const float* bc = (const float*)d_in[4];
  float* out = (float*)d_out;

  char* w = (char*)d_ws;
  __bf16* Apk = (__bf16*)w;  w += (size_t)BATCH * 1024 * 2;          // 16 MB
  __bf16* Bpk = (__bf16*)w;  w += (size_t)24 * 131072 * 2;           // 6 MB (stage-order)
  float* t1v  = (float*)w;   w += (size_t)BATCH * 24 * 4;
  int*   t1i  = (int*)w;     w += (size_t)BATCH * 24 * 4;
  float* t2v  = (float*)w;   w += (size_t)BATCH * 24 * 4;
  int*   t2i  = (int*)w;     w += (size_t)BATCH * 24 * 4;
  float* params = (float*)w; w += (size_t)BATCH * NCOMP * 4;         // 0.59 MB

  hipLaunchKernelGGL(k_pack, dim3(BATCH / 4 + 3072 / 4), dim3(256), 0, stream,
                     x, Wp, Wc, bc, Apk, Bpk, params);
  hipLaunchKernelGGL(k1_mfma, dim3(1536), dim3(256), 0, stream,
                     Apk, Bpk, bp, t1v, t1i, t2v, t2i);
  hipLaunchKernelGGL(k23_out, dim3(BATCH / 4), dim3(256), 0, stream,
                     x, Wp, bp, params, t1v, t1i, t2v, t2i, out);
}